// Round 1
// baseline (854.970 us; speedup 1.0000x reference)
//
#include <hip/hip_runtime.h>
#include <hip/hip_bf16.h>
#include <math.h>

#define ALPHA 0.2f

// Order-preserving float->uint key so atomicMax(uint) == float max.
__device__ __forceinline__ unsigned fkey(float f) {
  unsigned u = __float_as_uint(f);
  return (u & 0x80000000u) ? ~u : (u | 0x80000000u);
}
__device__ __forceinline__ float fdecode(unsigned k) {
  unsigned u = (k & 0x80000000u) ? (k ^ 0x80000000u) : ~k;
  return __uint_as_float(u);
}

__global__ __launch_bounds__(256) void k_init(unsigned* __restrict__ mkey,
                                              float* __restrict__ denom,
                                              float* __restrict__ acc, int N) {
  int i = blockIdx.x * 256 + threadIdx.x;
  if (i < N * 64) acc[i] = 0.f;
  if (i < N) { mkey[i] = 0u; denom[i] = 0.f; }
}

// hw = h @ W  (one wave per row; lane = output col), fused s1/s2 = hw . a1/a2
__global__ __launch_bounds__(256) void k_gemm(const float* __restrict__ h,
                                              const float* __restrict__ W,
                                              const float* __restrict__ a,
                                              float* __restrict__ hw,
                                              float* __restrict__ s1,
                                              float* __restrict__ s2, int N) {
  __shared__ float hrow[4 * 256];
  const int t = threadIdx.x;
  const int wave = t >> 6, lane = t & 63;
  const int row0 = blockIdx.x * 4;
  {
    int r = t >> 6, c = t & 63;
    float4 v = make_float4(0.f, 0.f, 0.f, 0.f);
    if (row0 + r < N) v = ((const float4*)(h + (size_t)(row0 + r) * 256))[c];
    ((float4*)hrow)[t] = v;
  }
  __syncthreads();
  const int row = row0 + wave;
  if (row >= N) return;
  const float* hr = hrow + wave * 256;
  float a0 = 0.f, a1 = 0.f, a2 = 0.f, a3 = 0.f;
  #pragma unroll 4
  for (int k = 0; k < 256; k += 4) {
    a0 = fmaf(hr[k + 0], W[(k + 0) * 64 + lane], a0);
    a1 = fmaf(hr[k + 1], W[(k + 1) * 64 + lane], a1);
    a2 = fmaf(hr[k + 2], W[(k + 2) * 64 + lane], a2);
    a3 = fmaf(hr[k + 3], W[(k + 3) * 64 + lane], a3);
  }
  float acc = (a0 + a1) + (a2 + a3);
  hw[(size_t)row * 64 + lane] = acc;
  // s1 = hw_row . a[0:64], s2 = hw_row . a[64:128] via butterfly reduce
  float p1 = acc * a[lane];
  float p2 = acc * a[64 + lane];
  #pragma unroll
  for (int off = 32; off; off >>= 1) {
    p1 += __shfl_xor(p1, off);
    p2 += __shfl_xor(p2, off);
  }
  if (lane == 0) { s1[row] = p1; s2[row] = p2; }
}

// per-edge score + segment max via atomicMax on ordered keys
__global__ __launch_bounds__(256) void k_emax(const int* __restrict__ dst,
                                              const int* __restrict__ src,
                                              const float* __restrict__ s1,
                                              const float* __restrict__ s2,
                                              unsigned* __restrict__ mkey, int E) {
  int i = blockIdx.x * 256 + threadIdx.x;
  if (i >= E) return;
  int d = dst[i], s = src[i];
  float v = s1[d] + s2[s];
  v = v > 0.f ? v : ALPHA * v;
  atomicMax(mkey + d, fkey(v));
}

// one wave per edge: lane d accumulates ex * hw[src][d] into acc[dst][d]
__global__ __launch_bounds__(256) void k_escat(const int* __restrict__ dst,
                                               const int* __restrict__ src,
                                               const float* __restrict__ s1,
                                               const float* __restrict__ s2,
                                               const unsigned* __restrict__ mkey,
                                               const float* __restrict__ hw,
                                               float* __restrict__ acc,
                                               float* __restrict__ denom,
                                               long long E) {
  long long gid = (long long)blockIdx.x * 256 + threadIdx.x;
  long long e = gid >> 6;
  int lane = threadIdx.x & 63;
  if (e >= E) return;
  int d = dst[e], s = src[e];
  float v = s1[d] + s2[s];
  v = v > 0.f ? v : ALPHA * v;
  float ex = expf(v - fdecode(mkey[d]));
  atomicAdd(acc + (size_t)d * 64 + lane, ex * hw[(size_t)s * 64 + lane]);
  if (lane == 0) atomicAdd(denom + d, ex);
}

// out = elu(acc / denom); empty segments (denom==0) -> 0
__global__ __launch_bounds__(256) void k_out(const float* __restrict__ acc,
                                             const float* __restrict__ denom,
                                             float* __restrict__ out, int N) {
  int i = blockIdx.x * 256 + threadIdx.x;
  if (i >= N * 64) return;
  float dn = denom[i >> 6];
  float v = dn != 0.f ? acc[i] / dn : 0.f;
  out[i] = v > 0.f ? v : expf(v) - 1.f;
}

extern "C" void kernel_launch(void* const* d_in, const int* in_sizes, int n_in,
                              void* d_out, int out_size, void* d_ws, size_t ws_size,
                              hipStream_t stream) {
  const float* h   = (const float*)d_in[0];
  const float* W   = (const float*)d_in[1];
  const float* a   = (const float*)d_in[2];
  const int*   dst = (const int*)d_in[3];
  const int*   src = (const int*)d_in[4];
  float* out = (float*)d_out;
  const int N = in_sizes[0] / 256;
  const int E = in_sizes[3];

  char* p = (char*)d_ws;
  float*    hw    = (float*)p;    p += (size_t)N * 64 * sizeof(float);
  float*    acc   = (float*)p;    p += (size_t)N * 64 * sizeof(float);
  float*    s1    = (float*)p;    p += (size_t)N * sizeof(float);
  float*    s2    = (float*)p;    p += (size_t)N * sizeof(float);
  float*    denom = (float*)p;    p += (size_t)N * sizeof(float);
  unsigned* mkey  = (unsigned*)p; p += (size_t)N * sizeof(unsigned);

  const int nb_n64 = (N * 64 + 255) / 256;
  k_init<<<nb_n64, 256, 0, stream>>>(mkey, denom, acc, N);
  k_gemm<<<(N + 3) / 4, 256, 0, stream>>>(h, W, a, hw, s1, s2, N);
  k_emax<<<(E + 255) / 256, 256, 0, stream>>>(dst, src, s1, s2, mkey, E);
  const long long tot = (long long)E * 64;
  k_escat<<<(int)((tot + 255) / 256), 256, 0, stream>>>(dst, src, s1, s2, mkey,
                                                        hw, acc, denom, E);
  k_out<<<nb_n64, 256, 0, stream>>>(acc, denom, out, N);
}

// Round 3
// 473.212 us; speedup vs baseline: 1.8067x; 1.8067x over previous
//
#include <hip/hip_runtime.h>
#include <hip/hip_bf16.h>
#include <math.h>

#define ALPHA 0.2f

// ---------------- zero counts/cursor ----------------
__global__ __launch_bounds__(256) void k_zero(int* __restrict__ counts,
                                              int* __restrict__ cursor, int N) {
  int i = blockIdx.x * 256 + threadIdx.x;
  if (i < N) { counts[i] = 0; cursor[i] = 0; }
}

// ---------------- tiled fp32 GEMM: hw = h @ W ----------------
// block: 256 threads, BM=128 rows x 64 cols. thread tile 8x4.
__global__ __launch_bounds__(256) void k_gemm(const float* __restrict__ h,
                                              const float* __restrict__ W,
                                              float* __restrict__ hw, int N) {
  __shared__ float hsT[32 * 132];  // hsT[k][r], stride 132 (pad, 16B aligned)
  __shared__ float ws[32 * 64];    // ws[k][c]
  const int tid = threadIdx.x;
  const int c0 = (tid & 15) * 4;
  const int r0 = (tid >> 4) * 8;
  const int row0 = blockIdx.x * 128;
  float acc[8][4] = {};
  for (int k0 = 0; k0 < 256; k0 += 32) {
    __syncthreads();
    #pragma unroll
    for (int s = 0; s < 4; ++s) {
      int f = tid + 256 * s;
      int r = f >> 3, kk = (f & 7) * 4;
      int row = row0 + r;
      float4 v = make_float4(0.f, 0.f, 0.f, 0.f);
      if (row < N) v = *(const float4*)(h + (size_t)row * 256 + k0 + kk);
      hsT[(kk + 0) * 132 + r] = v.x;
      hsT[(kk + 1) * 132 + r] = v.y;
      hsT[(kk + 2) * 132 + r] = v.z;
      hsT[(kk + 3) * 132 + r] = v.w;
    }
    #pragma unroll
    for (int s = 0; s < 2; ++s) {
      int f = tid + 256 * s;
      int kk = f >> 4, cc = (f & 15) * 4;
      *(float4*)(ws + kk * 64 + cc) =
          *(const float4*)(W + (size_t)(k0 + kk) * 64 + cc);
    }
    __syncthreads();
    #pragma unroll
    for (int k = 0; k < 32; ++k) {
      float4 wv = *(const float4*)(ws + k * 64 + c0);
      float4 ha = *(const float4*)(hsT + k * 132 + r0);
      float4 hb = *(const float4*)(hsT + k * 132 + r0 + 4);
      float hv[8] = {ha.x, ha.y, ha.z, ha.w, hb.x, hb.y, hb.z, hb.w};
      float wf[4] = {wv.x, wv.y, wv.z, wv.w};
      #pragma unroll
      for (int i = 0; i < 8; ++i)
        #pragma unroll
        for (int j = 0; j < 4; ++j)
          acc[i][j] = fmaf(hv[i], wf[j], acc[i][j]);
    }
  }
  #pragma unroll
  for (int i = 0; i < 8; ++i) {
    int row = row0 + r0 + i;
    if (row < N) {
      float4 o = make_float4(acc[i][0], acc[i][1], acc[i][2], acc[i][3]);
      *(float4*)(hw + (size_t)row * 64 + c0) = o;
    }
  }
}

// ---------------- s1/s2 = hw . a[:64], hw . a[64:] ----------------
__global__ __launch_bounds__(256) void k_s(const float* __restrict__ hw,
                                           const float* __restrict__ a,
                                           float* __restrict__ s1,
                                           float* __restrict__ s2, int N) {
  int n = blockIdx.x * 4 + (threadIdx.x >> 6);
  int lane = threadIdx.x & 63;
  if (n >= N) return;
  float v = hw[(size_t)n * 64 + lane];
  float p1 = v * a[lane];
  float p2 = v * a[64 + lane];
  #pragma unroll
  for (int o = 32; o; o >>= 1) {
    p1 += __shfl_xor(p1, o);
    p2 += __shfl_xor(p2, o);
  }
  if (lane == 0) { s1[n] = p1; s2[n] = p2; }
}

// ---------------- histogram of dst ----------------
__global__ __launch_bounds__(256) void k_hist(const int* __restrict__ dst,
                                              int* __restrict__ counts, int E) {
  int e = blockIdx.x * 256 + threadIdx.x;
  if (e < E) atomicAdd(counts + dst[e], 1);
}

// ---------------- exclusive scan (3 kernels, 2048 items/block) ----------------
__global__ __launch_bounds__(256) void k_scanA(const int* __restrict__ counts,
                                               int* __restrict__ offsets,
                                               int* __restrict__ bsum, int N) {
  __shared__ int lds[256];
  int tid = threadIdx.x;
  int base = blockIdx.x * 2048 + tid * 8;
  int v[8];
  int run = 0;
  #pragma unroll
  for (int i = 0; i < 8; ++i) {
    int t = (base + i < N) ? counts[base + i] : 0;
    v[i] = run;
    run += t;
  }
  lds[tid] = run;
  __syncthreads();
  for (int off = 1; off < 256; off <<= 1) {
    int t = 0;
    if (tid >= off) t = lds[tid - off];
    __syncthreads();
    if (tid >= off) lds[tid] += t;
    __syncthreads();
  }
  int prefix = tid > 0 ? lds[tid - 1] : 0;
  if (tid == 255) bsum[blockIdx.x] = lds[255];
  #pragma unroll
  for (int i = 0; i < 8; ++i)
    if (base + i < N) offsets[base + i] = prefix + v[i];
}

__global__ void k_scanB(const int* __restrict__ bsum, int* __restrict__ bscan,
                        int nb) {
  if (threadIdx.x == 0 && blockIdx.x == 0) {
    int run = 0;
    for (int b = 0; b < nb; ++b) { int t = bsum[b]; bscan[b] = run; run += t; }
  }
}

__global__ __launch_bounds__(256) void k_scanC(int* __restrict__ offsets,
                                               const int* __restrict__ bscan,
                                               int N, int E) {
  int i = blockIdx.x * 256 + threadIdx.x;
  if (i < N) offsets[i] += bscan[i >> 11];
  if (i == 0) offsets[N] = E;
}

// ---------------- fill CSR ----------------
__global__ __launch_bounds__(256) void k_fill(const int* __restrict__ dst,
                                              const int* __restrict__ src,
                                              const int* __restrict__ offsets,
                                              int* __restrict__ cursor,
                                              int* __restrict__ csr, int E) {
  int e = blockIdx.x * 256 + threadIdx.x;
  if (e >= E) return;
  int d = dst[e];
  int pos = offsets[d] + atomicAdd(cursor + d, 1);
  csr[pos] = src[e];
}

// ---------------- per-node softmax + aggregation + ELU ----------------
__global__ __launch_bounds__(256) void k_node(const int* __restrict__ off,
                                              const int* __restrict__ csr,
                                              const float* __restrict__ s1,
                                              const float* __restrict__ s2,
                                              const float* __restrict__ hw,
                                              float* __restrict__ out, int N) {
  int n = blockIdx.x * 4 + (threadIdx.x >> 6);
  int lane = threadIdx.x & 63;
  if (n >= N) return;
  int o0 = off[n], o1 = off[n + 1];
  int deg = o1 - o0;
  if (deg == 0) { out[(size_t)n * 64 + lane] = 0.f; return; }
  float s1n = s1[n];
  float acc = 0.f, esum;
  if (deg <= 64) {
    bool valid = lane < deg;
    int sj = valid ? csr[o0 + lane] : 0;
    float v = -INFINITY;
    if (valid) {
      v = s1n + s2[sj];
      v = v > 0.f ? v : ALPHA * v;
    }
    float m = v;
    #pragma unroll
    for (int o = 32; o; o >>= 1) m = fmaxf(m, __shfl_xor(m, o));
    float ex = valid ? expf(v - m) : 0.f;
    float es = ex;
    #pragma unroll
    for (int o = 32; o; o >>= 1) es += __shfl_xor(es, o);
    esum = es;
    for (int j = 0; j < deg; ++j) {
      float exj = __shfl(ex, j);
      int sjj = __shfl(sj, j);
      acc = fmaf(exj, hw[(size_t)sjj * 64 + lane], acc);
    }
  } else {
    float lm = -INFINITY;
    for (int j = lane; j < deg; j += 64) {
      int sj = csr[o0 + j];
      float v = s1n + s2[sj];
      v = v > 0.f ? v : ALPHA * v;
      lm = fmaxf(lm, v);
    }
    #pragma unroll
    for (int o = 32; o; o >>= 1) lm = fmaxf(lm, __shfl_xor(lm, o));
    float m = lm, les = 0.f;
    for (int j0 = 0; j0 < deg; j0 += 64) {
      int jj = j0 + lane;
      bool valid = jj < deg;
      int sj = valid ? csr[o0 + jj] : 0;
      float ex = 0.f;
      if (valid) {
        float v = s1n + s2[sj];
        v = v > 0.f ? v : ALPHA * v;
        ex = expf(v - m);
      }
      les += ex;
      int lim = min(64, deg - j0);
      for (int j = 0; j < lim; ++j) {
        float exj = __shfl(ex, j);
        int sjj = __shfl(sj, j);
        acc = fmaf(exj, hw[(size_t)sjj * 64 + lane], acc);
      }
    }
    #pragma unroll
    for (int o = 32; o; o >>= 1) les += __shfl_xor(les, o);
    esum = les;
  }
  float r = acc / esum;
  out[(size_t)n * 64 + lane] = r > 0.f ? r : expm1f(r);
}

extern "C" void kernel_launch(void* const* d_in, const int* in_sizes, int n_in,
                              void* d_out, int out_size, void* d_ws, size_t ws_size,
                              hipStream_t stream) {
  const float* h = (const float*)d_in[0];
  const float* W = (const float*)d_in[1];
  const float* a = (const float*)d_in[2];
  const int* dst = (const int*)d_in[3];
  const int* src = (const int*)d_in[4];
  float* out = (float*)d_out;
  const int N = in_sizes[0] / 256;
  const int E = in_sizes[3];

  char* p = (char*)d_ws;
  float* hw = (float*)p;      p += (size_t)N * 64 * sizeof(float);
  int* csr = (int*)p;         p += (size_t)E * sizeof(int);
  float* s1 = (float*)p;      p += (size_t)N * sizeof(float);
  float* s2 = (float*)p;      p += (size_t)N * sizeof(float);
  int* counts = (int*)p;      p += (size_t)N * sizeof(int);
  int* cursor = (int*)p;      p += (size_t)N * sizeof(int);
  int* offsets = (int*)p;     p += ((size_t)N + 4) * sizeof(int);
  int* bsum = (int*)p;        p += 64 * sizeof(int);
  int* bscan = (int*)p;       p += 64 * sizeof(int);

  const int nbN = (N + 255) / 256;
  const int nbE = (E + 255) / 256;
  const int nscan = (N + 2047) / 2048;

  k_zero<<<nbN, 256, 0, stream>>>(counts, cursor, N);
  k_gemm<<<(N + 127) / 128, 256, 0, stream>>>(h, W, hw, N);
  k_s<<<(N + 3) / 4, 256, 0, stream>>>(hw, a, s1, s2, N);
  k_hist<<<nbE, 256, 0, stream>>>(dst, counts, E);
  k_scanA<<<nscan, 256, 0, stream>>>(counts, offsets, bsum, N);
  k_scanB<<<1, 64, 0, stream>>>(bsum, bscan, nscan);
  k_scanC<<<nbN, 256, 0, stream>>>(offsets, bscan, N, E);
  k_fill<<<nbE, 256, 0, stream>>>(dst, src, offsets, cursor, csr, E);
  k_node<<<(N + 3) / 4, 256, 0, stream>>>(offsets, csr, s1, s2, hw, out, N);
}

// Round 6
// 459.791 us; speedup vs baseline: 1.8595x; 1.0292x over previous
//
#include <hip/hip_runtime.h>
#include <hip/hip_bf16.h>
#include <math.h>

#define ALPHA 0.2f

// ---------------- zero counts ----------------
__global__ __launch_bounds__(256) void k_zero(int* __restrict__ counts, int N) {
  int i = blockIdx.x * 256 + threadIdx.x;
  if (i < N) counts[i] = 0;
}

// ---------------- tiled fp32 GEMM: hw = h @ W ----------------
// block: 256 threads, BM=128 rows x 64 cols. thread tile 8x4.
__global__ __launch_bounds__(256) void k_gemm(const float* __restrict__ h,
                                              const float* __restrict__ W,
                                              float* __restrict__ hw, int N) {
  __shared__ float hsT[32 * 132];  // hsT[k][r], stride 132 (pad)
  __shared__ float ws[32 * 64];    // ws[k][c]
  const int tid = threadIdx.x;
  const int c0 = (tid & 15) * 4;
  const int r0 = (tid >> 4) * 8;
  const int row0 = blockIdx.x * 128;
  float acc[8][4] = {};
  for (int k0 = 0; k0 < 256; k0 += 32) {
    __syncthreads();
    #pragma unroll
    for (int s = 0; s < 4; ++s) {
      int f = tid + 256 * s;
      int r = f >> 3, kk = (f & 7) * 4;
      int row = row0 + r;
      float4 v = make_float4(0.f, 0.f, 0.f, 0.f);
      if (row < N) v = *(const float4*)(h + (size_t)row * 256 + k0 + kk);
      hsT[(kk + 0) * 132 + r] = v.x;
      hsT[(kk + 1) * 132 + r] = v.y;
      hsT[(kk + 2) * 132 + r] = v.z;
      hsT[(kk + 3) * 132 + r] = v.w;
    }
    #pragma unroll
    for (int s = 0; s < 2; ++s) {
      int f = tid + 256 * s;
      int kk = f >> 4, cc = (f & 15) * 4;
      *(float4*)(ws + kk * 64 + cc) =
          *(const float4*)(W + (size_t)(k0 + kk) * 64 + cc);
    }
    __syncthreads();
    #pragma unroll
    for (int k = 0; k < 32; ++k) {
      float4 wv = *(const float4*)(ws + k * 64 + c0);
      float4 ha = *(const float4*)(hsT + k * 132 + r0);
      float4 hb = *(const float4*)(hsT + k * 132 + r0 + 4);
      float hv[8] = {ha.x, ha.y, ha.z, ha.w, hb.x, hb.y, hb.z, hb.w};
      float wf[4] = {wv.x, wv.y, wv.z, wv.w};
      #pragma unroll
      for (int i = 0; i < 8; ++i)
        #pragma unroll
        for (int j = 0; j < 4; ++j)
          acc[i][j] = fmaf(hv[i], wf[j], acc[i][j]);
    }
  }
  #pragma unroll
  for (int i = 0; i < 8; ++i) {
    int row = row0 + r0 + i;
    if (row < N) {
      float4 o = make_float4(acc[i][0], acc[i][1], acc[i][2], acc[i][3]);
      *(float4*)(hw + (size_t)row * 64 + c0) = o;
    }
  }
}

// ---------------- s1/s2 = hw . a[:64], hw . a[64:] ----------------
__global__ __launch_bounds__(256) void k_s(const float* __restrict__ hw,
                                           const float* __restrict__ a,
                                           float* __restrict__ s1,
                                           float* __restrict__ s2, int N) {
  int n = blockIdx.x * 4 + (threadIdx.x >> 6);
  int lane = threadIdx.x & 63;
  if (n >= N) return;
  float v = hw[(size_t)n * 64 + lane];
  float p1 = v * a[lane];
  float p2 = v * a[64 + lane];
  #pragma unroll
  for (int o = 32; o; o >>= 1) {
    p1 += __shfl_xor(p1, o);
    p2 += __shfl_xor(p2, o);
  }
  if (lane == 0) { s1[n] = p1; s2[n] = p2; }
}

// ---------------- histogram of dst ----------------
__global__ __launch_bounds__(256) void k_hist(const int* __restrict__ dst,
                                              int* __restrict__ counts, int E) {
  int e = blockIdx.x * 256 + threadIdx.x;
  if (e < E) atomicAdd(counts + dst[e], 1);
}

// ---------------- exclusive scan (3 kernels, 2048 items/block) ----------------
__global__ __launch_bounds__(256) void k_scanA(const int* __restrict__ counts,
                                               int* __restrict__ offsets,
                                               int* __restrict__ bsum, int N) {
  __shared__ int lds[256];
  int tid = threadIdx.x;
  int base = blockIdx.x * 2048 + tid * 8;
  int v[8];
  int run = 0;
  #pragma unroll
  for (int i = 0; i < 8; ++i) {
    int t = (base + i < N) ? counts[base + i] : 0;
    v[i] = run;
    run += t;
  }
  lds[tid] = run;
  __syncthreads();
  for (int off = 1; off < 256; off <<= 1) {
    int t = 0;
    if (tid >= off) t = lds[tid - off];
    __syncthreads();
    if (tid >= off) lds[tid] += t;
    __syncthreads();
  }
  int prefix = tid > 0 ? lds[tid - 1] : 0;
  if (tid == 255) bsum[blockIdx.x] = lds[255];
  #pragma unroll
  for (int i = 0; i < 8; ++i)
    if (base + i < N) offsets[base + i] = prefix + v[i];
}

__global__ void k_scanB(const int* __restrict__ bsum, int* __restrict__ bscan,
                        int nb) {
  if (threadIdx.x == 0 && blockIdx.x == 0) {
    int run = 0;
    for (int b = 0; b < nb; ++b) { int t = bsum[b]; bscan[b] = run; run += t; }
  }
}

// finalize offsets, and seed cursor = offsets (k_fill bumps it)
__global__ __launch_bounds__(256) void k_scanC(int* __restrict__ offsets,
                                               int* __restrict__ cursor,
                                               const int* __restrict__ bscan,
                                               int N, int E) {
  int i = blockIdx.x * 256 + threadIdx.x;
  if (i < N) {
    int v = offsets[i] + bscan[i >> 11];
    offsets[i] = v;
    cursor[i] = v;
  }
  if (i == 0) offsets[N] = E;
}

// ---------------- fill CSR (single atomic per edge) ----------------
__global__ __launch_bounds__(256) void k_fill(const int* __restrict__ dst,
                                              const int* __restrict__ src,
                                              int* __restrict__ cursor,
                                              int* __restrict__ csr, int E) {
  int e = blockIdx.x * 256 + threadIdx.x;
  if (e >= E) return;
  int pos = atomicAdd(cursor + dst[e], 1);
  csr[pos] = src[e];
}

// ---------------- per-node softmax + aggregation + ELU ----------------
// one wave per node. Aggregation: lane = (edge_group<<4)|chunk -> 4 rows
// gathered per float4 instruction (1KB/wave/instr), deg/4 trip count.
__global__ __launch_bounds__(256) void k_node(const int* __restrict__ off,
                                              const int* __restrict__ csr,
                                              const float* __restrict__ s1,
                                              const float* __restrict__ s2,
                                              const float* __restrict__ hw,
                                              float* __restrict__ out, int N) {
  int n = blockIdx.x * 4 + (threadIdx.x >> 6);
  int lane = threadIdx.x & 63;
  if (n >= N) return;
  int o0 = off[n], o1 = off[n + 1];
  int deg = o1 - o0;
  float4* out4 = (float4*)(out + (size_t)n * 64);
  if (deg == 0) {
    if (lane < 16) out4[lane] = make_float4(0.f, 0.f, 0.f, 0.f);
    return;
  }
  float s1n = s1[n];
  if (deg <= 64) {
    bool valid = lane < deg;
    int sj = valid ? csr[o0 + lane] : 0;
    float v = -INFINITY;
    if (valid) {
      v = s1n + s2[sj];
      v = v > 0.f ? v : ALPHA * v;
    }
    float m = v;
    #pragma unroll
    for (int o = 32; o; o >>= 1) m = fmaxf(m, __shfl_xor(m, o));
    float ex = valid ? expf(v - m) : 0.f;
    float es = ex;
    #pragma unroll
    for (int o = 32; o; o >>= 1) es += __shfl_xor(es, o);
    // ---- aggregation: 4 edges per iteration ----
    const int grp = lane >> 4, ch = lane & 15;
    const float4* hw4 = (const float4*)hw;
    float4 acc = make_float4(0.f, 0.f, 0.f, 0.f);
    for (int j0 = 0; j0 < deg; j0 += 4) {
      int e = j0 + grp;
      float exj = __shfl(ex, e & 63);
      int sjj = __shfl(sj, e & 63);
      if (e < deg) {
        float4 vv = hw4[(size_t)sjj * 16 + ch];
        acc.x = fmaf(exj, vv.x, acc.x);
        acc.y = fmaf(exj, vv.y, acc.y);
        acc.z = fmaf(exj, vv.z, acc.z);
        acc.w = fmaf(exj, vv.w, acc.w);
      }
    }
    // reduce across the 4 edge-groups (lanes l, l^16, l^32, l^48)
    acc.x += __shfl_xor(acc.x, 16);
    acc.y += __shfl_xor(acc.y, 16);
    acc.z += __shfl_xor(acc.z, 16);
    acc.w += __shfl_xor(acc.w, 16);
    acc.x += __shfl_xor(acc.x, 32);
    acc.y += __shfl_xor(acc.y, 32);
    acc.z += __shfl_xor(acc.z, 32);
    acc.w += __shfl_xor(acc.w, 32);
    if (lane < 16) {
      float inv = 1.f / es;
      float4 r;
      r.x = acc.x * inv; r.x = r.x > 0.f ? r.x : expm1f(r.x);
      r.y = acc.y * inv; r.y = r.y > 0.f ? r.y : expm1f(r.y);
      r.z = acc.z * inv; r.z = r.z > 0.f ? r.z : expm1f(r.z);
      r.w = acc.w * inv; r.w = r.w > 0.f ? r.w : expm1f(r.w);
      out4[lane] = r;
    }
  } else {
    // rare fallback: deg > 64 (strided, scalar)
    float lm = -INFINITY;
    for (int j = lane; j < deg; j += 64) {
      int sj = csr[o0 + j];
      float v = s1n + s2[sj];
      v = v > 0.f ? v : ALPHA * v;
      lm = fmaxf(lm, v);
    }
    #pragma unroll
    for (int o = 32; o; o >>= 1) lm = fmaxf(lm, __shfl_xor(lm, o));
    float m = lm, les = 0.f, acc = 0.f;
    for (int j0 = 0; j0 < deg; j0 += 64) {
      int jj = j0 + lane;
      bool valid = jj < deg;
      int sj = valid ? csr[o0 + jj] : 0;
      float ex = 0.f;
      if (valid) {
        float v = s1n + s2[sj];
        v = v > 0.f ? v : ALPHA * v;
        ex = expf(v - m);
      }
      les += ex;
      int lim = min(64, deg - j0);
      for (int j = 0; j < lim; ++j) {
        float exj = __shfl(ex, j);
        int sjj = __shfl(sj, j);
        acc = fmaf(exj, hw[(size_t)sjj * 64 + lane], acc);
      }
    }
    #pragma unroll
    for (int o = 32; o; o >>= 1) les += __shfl_xor(les, o);
    float r = acc / les;
    out[(size_t)n * 64 + lane] = r > 0.f ? r : expm1f(r);
  }
}

extern "C" void kernel_launch(void* const* d_in, const int* in_sizes, int n_in,
                              void* d_out, int out_size, void* d_ws, size_t ws_size,
                              hipStream_t stream) {
  const float* h = (const float*)d_in[0];
  const float* W = (const float*)d_in[1];
  const float* a = (const float*)d_in[2];
  const int* dst = (const int*)d_in[3];
  const int* src = (const int*)d_in[4];
  float* out = (float*)d_out;
  const int N = in_sizes[0] / 256;
  const int E = in_sizes[3];

  char* p = (char*)d_ws;
  float* hw = (float*)p;      p += (size_t)N * 64 * sizeof(float);
  int* csr = (int*)p;         p += (size_t)E * sizeof(int);
  float* s1 = (float*)p;      p += (size_t)N * sizeof(float);
  float* s2 = (float*)p;      p += (size_t)N * sizeof(float);
  int* counts = (int*)p;      p += (size_t)N * sizeof(int);
  int* cursor = (int*)p;      p += (size_t)N * sizeof(int);
  int* offsets = (int*)p;     p += ((size_t)N + 4) * sizeof(int);
  int* bsum = (int*)p;        p += 64 * sizeof(int);
  int* bscan = (int*)p;       p += 64 * sizeof(int);

  const int nbN = (N + 255) / 256;
  const int nbE = (E + 255) / 256;
  const int nscan = (N + 2047) / 2048;

  k_zero<<<nbN, 256, 0, stream>>>(counts, N);
  k_gemm<<<(N + 127) / 128, 256, 0, stream>>>(h, W, hw, N);
  k_s<<<(N + 3) / 4, 256, 0, stream>>>(hw, a, s1, s2, N);
  k_hist<<<nbE, 256, 0, stream>>>(dst, counts, E);
  k_scanA<<<nscan, 256, 0, stream>>>(counts, offsets, bsum, N);
  k_scanB<<<1, 64, 0, stream>>>(bsum, bscan, nscan);
  k_scanC<<<nbN, 256, 0, stream>>>(offsets, cursor, bscan, N, E);
  k_fill<<<nbE, 256, 0, stream>>>(dst, src, cursor, csr, E);
  k_node<<<(N + 3) / 4, 256, 0, stream>>>(offsets, csr, s1, s2, hw, out, N);
}